// Round 4
// baseline (56.005 us; speedup 1.0000x reference)
//
#include <hip/hip_runtime.h>

// Problem constants (fixed by the reference)
#define BB 32
#define TL 4096
#define KK 128
#define HH 8
#define SCALE2 0.08838834764831845f  // K^-0.5 = (K^-0.25)^2

#define NCHB 16   // chunks for dot pass   (rows per chunk = 256)
#define NCHC 16   // chunks for accum pass (rows per chunk = 256)

// workspace layout (float offsets)
#define OFF_WK  0
#define N_WK    (BB*HH*KK)          // 32768
#define OFF_P   (OFF_WK + N_WK)
#define N_P     (BB*TL*HH)          // 1048576
#define OFF_DEN (OFF_P + N_P)
#define N_DEN   (BB*HH*NCHB)        // 4096
#define OFF_XA  (OFF_DEN + N_DEN)
#define N_XA    (BB*NCHC*HH*KK)     // 524288

// ---------------------------------------------------------------------------
// Kernel A: wk_eff[b,h,j] = scale^2 * sum_c Wk[j, h*128+c] * qh[b,h,c]
//           qh[b,h,c]     = sum_c' x_glob[b,c'] * Wq[c', h*128+c]
// grid = B*H blocks, 128 threads
// ---------------------------------------------------------------------------
__global__ __launch_bounds__(128) void sa_kA(
    const float* __restrict__ xg, const float* __restrict__ Wq,
    const float* __restrict__ Wk, float* __restrict__ wk_eff) {
  int bh = blockIdx.x;
  int b = bh >> 3, h = bh & 7;
  int t = threadIdx.x;
  __shared__ float xgs[KK];
  __shared__ float qh[KK];
  xgs[t] = xg[b * KK + t];
  __syncthreads();
  // qh[c = t]
  float acc = 0.f;
  const float* wq = Wq + h * KK + t;         // Wq[c'][h*128 + t], coalesced over t
  for (int c2 = 0; c2 < KK; ++c2) acc += xgs[c2] * wq[c2 * (HH * KK)];
  qh[t] = acc;
  __syncthreads();
  // wk_eff[j = t]
  const float4* wk4 = (const float4*)(Wk + t * (HH * KK) + h * KK);
  const float4* qh4 = (const float4*)qh;
  float acc2 = 0.f;
  #pragma unroll 8
  for (int c4 = 0; c4 < KK / 4; ++c4) {
    float4 a = wk4[c4];
    float4 q4 = qh4[c4];   // broadcast from LDS
    acc2 += a.x * q4.x + a.y * q4.y + a.z * q4.z + a.w * q4.w;
  }
  wk_eff[bh * KK + t] = acc2 * SCALE2;
}

// ---------------------------------------------------------------------------
// Kernel B: dot pass. p[b][l][h] = exp(x[b,l,:] . wk_eff[b,h,:])
//           denP[(b*H+h)*NCHB + chunk] = sum_l_in_chunk p
// 16-lane groups: each group owns one row per iteration, lane covers 8 cols,
// butterfly __shfl_xor reduce within the group (guaranteed-coalesced x reads).
// grid = (NCHB, B), 512 threads
// ---------------------------------------------------------------------------
__global__ __launch_bounds__(512) void sa_kB(
    const float* __restrict__ x, const float* __restrict__ wk_eff,
    float* __restrict__ pbuf, float* __restrict__ denP) {
  const int chunk = blockIdx.x;
  const int b = blockIdx.y;
  const int t = threadIdx.x;
  const int lane16 = t & 15;
  const int g = t >> 4;              // 0..31 row-groups
  // per-thread register slice of wk_eff: wkr[h][j], c = lane16*8 + j
  float wkr[HH][8];
  const float* wkb = wk_eff + (b * HH) * KK + lane16 * 8;
  #pragma unroll
  for (int h = 0; h < HH; ++h) {
    float4 a = *(const float4*)(wkb + h * KK);
    float4 c = *(const float4*)(wkb + h * KK + 4);
    wkr[h][0] = a.x; wkr[h][1] = a.y; wkr[h][2] = a.z; wkr[h][3] = a.w;
    wkr[h][4] = c.x; wkr[h][5] = c.y; wkr[h][6] = c.z; wkr[h][7] = c.w;
  }
  float den = 0.f;
  const int rows = TL / NCHB;        // 256
  const int l0 = chunk * rows;
  for (int i = 0; i < rows / 32; ++i) {
    int l = l0 + g + i * 32;
    const float* xr = x + ((size_t)b * TL + l) * KK + lane16 * 8;
    float4 xa = *(const float4*)xr;
    float4 xb = *(const float4*)(xr + 4);
    float part[HH];
    #pragma unroll
    for (int h = 0; h < HH; ++h) {
      part[h] = xa.x * wkr[h][0] + xa.y * wkr[h][1] + xa.z * wkr[h][2] + xa.w * wkr[h][3]
              + xb.x * wkr[h][4] + xb.y * wkr[h][5] + xb.z * wkr[h][6] + xb.w * wkr[h][7];
    }
    #pragma unroll
    for (int s = 1; s < 16; s <<= 1) {
      #pragma unroll
      for (int h = 0; h < HH; ++h) part[h] += __shfl_xor(part[h], s, 64);
    }
    if (lane16 < 8) {
      float d = part[0];
      #pragma unroll
      for (int h = 1; h < HH; ++h) d = (lane16 == h) ? part[h] : d;
      float p = __expf(d);           // dot ~ N(0,1): no max-subtraction needed
      pbuf[((size_t)b * TL + l) * HH + lane16] = p;
      den += p;
    }
  }
  __shared__ float denl[32][8];
  if (lane16 < 8) denl[g][lane16] = den;
  __syncthreads();
  if (t < 8) {
    float s = 0.f;
    for (int gg = 0; gg < 32; ++gg) s += denl[gg][t];
    denP[(b * HH + t) * NCHB + chunk] = s;
  }
}

// ---------------------------------------------------------------------------
// Kernel C: xattnP[b,chunk,h,c] = sum_l_in_chunk p[b,l,h] * x[b,l,c]
// thread: c4 = t%32 (4 cols via float4), rg = t/32 (16 row-streams), 32 accs.
// LDS tree-reduce over rg. grid = (NCHC, B), 512 threads.
// ---------------------------------------------------------------------------
__global__ __launch_bounds__(512) void sa_kC(
    const float* __restrict__ x, const float* __restrict__ pbuf,
    float* __restrict__ xattnP) {
  const int chunk = blockIdx.x;
  const int b = blockIdx.y;
  const int t = threadIdx.x;
  const int c4 = t & 31;
  const int rg = t >> 5;             // 0..15
  float acc[HH][4];
  #pragma unroll
  for (int h = 0; h < HH; ++h) {
    acc[h][0] = 0.f; acc[h][1] = 0.f; acc[h][2] = 0.f; acc[h][3] = 0.f;
  }
  const int rows = TL / NCHC;        // 256
  const int l0 = chunk * rows;
  for (int i = 0; i < rows / 16; ++i) {
    int l = l0 + rg + i * 16;
    float4 xv = *(const float4*)(x + ((size_t)b * TL + l) * KK + c4 * 4);
    float4 pa = *(const float4*)(pbuf + ((size_t)b * TL + l) * HH);
    float4 pb = *(const float4*)(pbuf + ((size_t)b * TL + l) * HH + 4);
    float pv[8] = {pa.x, pa.y, pa.z, pa.w, pb.x, pb.y, pb.z, pb.w};
    #pragma unroll
    for (int h = 0; h < HH; ++h) {
      acc[h][0] += pv[h] * xv.x;
      acc[h][1] += pv[h] * xv.y;
      acc[h][2] += pv[h] * xv.z;
      acc[h][3] += pv[h] * xv.w;
    }
  }
  // reduce over the 16 rg streams: 32 KB LDS, fold 16->8 then tree
  __shared__ float red[8][HH * KK];
  if (rg >= 8) {
    #pragma unroll
    for (int h = 0; h < HH; ++h)
      *(float4*)&red[rg - 8][h * KK + c4 * 4] = make_float4(acc[h][0], acc[h][1], acc[h][2], acc[h][3]);
  }
  __syncthreads();
  if (rg < 8) {
    #pragma unroll
    for (int h = 0; h < HH; ++h) {
      float4* dst = (float4*)&red[rg][h * KK + c4 * 4];
      float4 o = *dst;
      o.x += acc[h][0]; o.y += acc[h][1]; o.z += acc[h][2]; o.w += acc[h][3];
      *dst = o;
    }
  }
  __syncthreads();
  #pragma unroll
  for (int s = 4; s >= 1; s >>= 1) {
    if (rg < s) {
      #pragma unroll
      for (int h = 0; h < HH; ++h) {
        float4* dst = (float4*)&red[rg][h * KK + c4 * 4];
        float4 o = *(float4*)&red[rg + s][h * KK + c4 * 4];
        float4 d0 = *dst;
        d0.x += o.x; d0.y += o.y; d0.z += o.z; d0.w += o.w;
        *dst = d0;
      }
    }
    __syncthreads();
  }
  const int base = (b * NCHC + chunk) * (HH * KK);
  for (int v = t; v < HH * KK; v += 512) xattnP[base + v] = red[0][v];
}

// ---------------------------------------------------------------------------
// Kernel D: per (b,h): den = sum chunks; u = xattn/den; s = u @ Wv_h;
//           out[b,:] += s @ Wu_hslice (+ bu once, from h==0 block)
// grid = B*H blocks, 128 threads. d_out zeroed by hipMemsetAsync beforehand.
// ---------------------------------------------------------------------------
__global__ __launch_bounds__(128) void sa_kD(
    const float* __restrict__ xattnP, const float* __restrict__ denP,
    const float* __restrict__ Wv, const float* __restrict__ Wu,
    const float* __restrict__ bu, float* __restrict__ out) {
  const int bh = blockIdx.x;
  const int b = bh >> 3, h = bh & 7;
  const int t = threadIdx.x;
  float den = 0.f;
  #pragma unroll
  for (int cb = 0; cb < NCHB; ++cb) den += denP[(b * HH + h) * NCHB + cb];
  float acc = 0.f;
  #pragma unroll
  for (int ch = 0; ch < NCHC; ++ch)
    acc += xattnP[(b * NCHC + ch) * (HH * KK) + h * KK + t];
  __shared__ float u[KK];
  u[t] = acc / den;
  __syncthreads();
  // s[k = t] = sum_c u[c] * Wv[c, h*128 + k]
  float sk = 0.f;
  const float* wv = Wv + h * KK + t;
  for (int c = 0; c < KK; ++c) sk += u[c] * wv[c * (HH * KK)];
  __shared__ float sl[KK];
  sl[t] = sk;
  __syncthreads();
  // partial out[c' = t] over this h's K-slice of Wu
  float po = (h == 0) ? bu[t] : 0.f;
  const float* wu = Wu + (h * KK) * KK + t;
  for (int k = 0; k < KK; ++k) po += sl[k] * wu[k * KK];
  atomicAdd(&out[b * KK + t], po);
}

// ---------------------------------------------------------------------------
extern "C" void kernel_launch(void* const* d_in, const int* in_sizes, int n_in,
                              void* d_out, int out_size, void* d_ws, size_t ws_size,
                              hipStream_t stream) {
  const float* x  = (const float*)d_in[0];   // (32, 4096, 128)
  const float* xg = (const float*)d_in[1];   // (32, 1, 128)
  const float* Wq = (const float*)d_in[2];   // (128, 1024)
  const float* Wk = (const float*)d_in[3];   // (128, 1024)
  const float* Wv = (const float*)d_in[4];   // (128, 1024)
  const float* Wu = (const float*)d_in[5];   // (1024, 128)
  const float* bu = (const float*)d_in[6];   // (128,)
  float* out = (float*)d_out;                // (32, 128)

  float* ws     = (float*)d_ws;
  float* wk_eff = ws + OFF_WK;
  float* pbuf   = ws + OFF_P;
  float* denP   = ws + OFF_DEN;
  float* xattnP = ws + OFF_XA;

  hipMemsetAsync(d_out, 0, (size_t)out_size * sizeof(float), stream);
  sa_kA<<<dim3(BB * HH), dim3(128), 0, stream>>>(xg, Wq, Wk, wk_eff);
  sa_kB<<<dim3(NCHB, BB), dim3(512), 0, stream>>>(x, wk_eff, pbuf, denP);
  sa_kC<<<dim3(NCHC, BB), dim3(512), 0, stream>>>(x, pbuf, xattnP);
  sa_kD<<<dim3(BB * HH), dim3(128), 0, stream>>>(xattnP, denP, Wv, Wu, bu, out);
}